// Round 2
// baseline (31725.739 us; speedup 1.0000x reference)
//
#include <hip/hip_runtime.h>
#include <hip/hip_bf16.h>

#define N_NODES 100000
#define N_EDGES 1600000
#define N_GRAPHS 1024
#define F_NODE 16
#define F_EDGE 8
#define F_GRAPH 10
#define HD 64
#define HD2 128
#define GEN_EPS 1e-7f

// h[n][f] = node_b[f] + sum_k x[n][k]*node_W[k][f]
__global__ void __launch_bounds__(256) k_node_embed(
        const float* __restrict__ x, const float* __restrict__ W,
        const float* __restrict__ b, float* __restrict__ h) {
    __shared__ float sW[F_NODE * HD];
    __shared__ float sb[HD];
    for (int i = threadIdx.x; i < F_NODE * HD; i += 256) sW[i] = W[i];
    if (threadIdx.x < HD) sb[threadIdx.x] = b[threadIdx.x];
    __syncthreads();
    int t = blockIdx.x * 256 + threadIdx.x;
    if (t >= N_NODES * HD) return;
    int n = t >> 6, f = t & 63;
    const float* xr = x + (size_t)n * F_NODE;
    float acc = sb[f];
#pragma unroll
    for (int k = 0; k < F_NODE; k++) acc += xr[k] * sW[k * HD + f];
    h[t] = acc;
}

// One thread per edge. msg[f] = relu(h[src][f] + ea[f]) + eps (ea recomputed
// from edge_attr @ edge_W). Softmax WITHOUT max-subtraction (msg is O(1),
// exp-safe): denom[d][f] += exp(msg), num[d][f] += msg*exp(msg).
__global__ void __launch_bounds__(256) k_edge_pass(
        const float* __restrict__ h,
        const int* __restrict__ src, const int* __restrict__ dst,
        const float* __restrict__ eattr,
        const float* __restrict__ eW, const float* __restrict__ eb,
        float* __restrict__ denom, float* __restrict__ num) {
    __shared__ float sW[F_EDGE * HD];
    __shared__ float sb[HD];
    for (int i = threadIdx.x; i < F_EDGE * HD; i += 256) sW[i] = eW[i];
    if (threadIdx.x < HD) sb[threadIdx.x] = eb[threadIdx.x];
    __syncthreads();
    int e = blockIdx.x * 256 + threadIdx.x;
    if (e >= N_EDGES) return;
    int s = src[e], d = dst[e];
    const float4* ap = reinterpret_cast<const float4*>(eattr + (size_t)e * F_EDGE);
    float4 a0 = ap[0], a1 = ap[1];
    float a[8] = {a0.x, a0.y, a0.z, a0.w, a1.x, a1.y, a1.z, a1.w};
    float hr[HD];
    const float4* hp = reinterpret_cast<const float4*>(h + (size_t)s * HD);
#pragma unroll
    for (int i = 0; i < 16; i++) {
        float4 v = hp[i];
        hr[4 * i + 0] = v.x; hr[4 * i + 1] = v.y;
        hr[4 * i + 2] = v.z; hr[4 * i + 3] = v.w;
    }
    float* dr = denom + (size_t)d * HD;
    float* nr = num + (size_t)d * HD;
#pragma unroll
    for (int f = 0; f < HD; f++) {
        float eaf = sb[f];
#pragma unroll
        for (int k = 0; k < 8; k++) eaf += a[k] * sW[k * HD + f];
        float msg = fmaxf(hr[f] + eaf, 0.f) + GEN_EPS;
        float ev = __expf(msg);
        unsafeAtomicAdd(dr + f, ev);
        unsafeAtomicAdd(nr + f, msg * ev);
    }
}

// Fused GENConv MLP: out = h + num/max(denom,1e-16);
// hid = relu(out@W1+b1) (kept in LDS); h' = relu(hid@W2+b2).
// 64 nodes per block, processed 4 at a time. LDS ~68 KB -> 2 blocks/CU.
__global__ void __launch_bounds__(256) k_mlp(
        const float* __restrict__ h, const float* __restrict__ denom,
        const float* __restrict__ num,
        const float* __restrict__ W1, const float* __restrict__ b1,
        const float* __restrict__ W2, const float* __restrict__ b2,
        float* __restrict__ hout) {
    __shared__ float sW1[HD * HD2];   // 32 KB
    __shared__ float sW2[HD2 * HD];   // 32 KB
    __shared__ float sb1[HD2];
    __shared__ float sb2[HD];
    __shared__ float sOut[4][HD];
    __shared__ float sHid[4][HD2];
    for (int i = threadIdx.x; i < HD * HD2; i += 256) {
        sW1[i] = W1[i];
        sW2[i] = W2[i];
    }
    if (threadIdx.x < HD2) sb1[threadIdx.x] = b1[threadIdx.x];
    if (threadIdx.x < HD) sb2[threadIdx.x] = b2[threadIdx.x];
    __syncthreads();
    int block_n0 = blockIdx.x * 64;
    for (int it = 0; it < 16; it++) {
        int n0 = block_n0 + it * 4;
        {
            int nl = threadIdx.x >> 6, f = threadIdx.x & 63;
            int n = n0 + nl;
            float o = 0.f;
            if (n < N_NODES) {
                size_t idx = (size_t)n * HD + f;
                o = h[idx] + num[idx] / fmaxf(denom[idx], 1e-16f);
            }
            sOut[nl][f] = o;
        }
        __syncthreads();
        {
            int j = threadIdx.x & 127;
            int nlb = threadIdx.x >> 7;
#pragma unroll
            for (int rep = 0; rep < 2; rep++) {
                int nl = nlb + rep * 2;
                float acc = sb1[j];
#pragma unroll
                for (int f = 0; f < HD; f++) acc += sOut[nl][f] * sW1[f * HD2 + j];
                sHid[nl][j] = fmaxf(acc, 0.f);
            }
        }
        __syncthreads();
        {
            int nl = threadIdx.x >> 6, f = threadIdx.x & 63;
            int n = n0 + nl;
            float acc = sb2[f];
#pragma unroll
            for (int jj = 0; jj < HD2; jj++) acc += sHid[nl][jj] * sW2[jj * HD + f];
            if (n < N_NODES) hout[(size_t)n * HD + f] = fmaxf(acc, 0.f);
        }
        __syncthreads();
    }
}

__global__ void __launch_bounds__(256) k_pool(
        const float* __restrict__ h, const int* __restrict__ batch,
        float* __restrict__ gsum, float* __restrict__ gcnt) {
    int t = blockIdx.x * 256 + threadIdx.x;
    if (t >= N_NODES * HD) return;
    int n = t >> 6, f = t & 63;
    int g = batch[n];
    unsafeAtomicAdd(gsum + (size_t)g * HD + f, h[t]);
    if (f == 0) unsafeAtomicAdd(gcnt + g, 1.0f);
}

__global__ void __launch_bounds__(64) k_head(
        const float* __restrict__ gsum, const float* __restrict__ gcnt,
        const float* __restrict__ gattr,
        const float* __restrict__ d1W, const float* __restrict__ d1b,
        const float* __restrict__ d2W, const float* __restrict__ d2b,
        const float* __restrict__ oW, const float* __restrict__ ob,
        float* __restrict__ out) {
    int g = blockIdx.x;
    __shared__ float si[HD + F_GRAPH];
    __shared__ float s1[32], s2[32];
    int t = threadIdx.x;
    float cnt = fmaxf(gcnt[g], 1.0f);
    if (t < HD) si[t] = gsum[(size_t)g * HD + t] / cnt;
    if (t < F_GRAPH) si[HD + t] = gattr[(size_t)g * F_GRAPH + t];
    __syncthreads();
    if (t < 32) {
        float acc = d1b[t];
        for (int i = 0; i < HD + F_GRAPH; i++) acc += si[i] * d1W[i * 32 + t];
        s1[t] = fmaxf(acc, 0.f);
    }
    __syncthreads();
    if (t < 32) {
        float acc = d2b[t];
        for (int i = 0; i < 32; i++) acc += s1[i] * d2W[i * 32 + t];
        s2[t] = fmaxf(acc, 0.f);
    }
    __syncthreads();
    if (t == 0) {
        float acc = ob[0];
        for (int i = 0; i < 32; i++) acc += s2[i] * oW[i];
        out[g] = 1.f / (1.f + __expf(-acc));
    }
}

extern "C" void kernel_launch(void* const* d_in, const int* in_sizes, int n_in,
                              void* d_out, int out_size, void* d_ws, size_t ws_size,
                              hipStream_t stream) {
    const float* x     = (const float*)d_in[0];
    const float* eattr = (const float*)d_in[1];
    const float* gattr = (const float*)d_in[2];
    const int*   eidx  = (const int*)d_in[3];
    const int*   batch = (const int*)d_in[4];
    const float* nodeW = (const float*)d_in[5];
    const float* nodeb = (const float*)d_in[6];
    const float* edgeW = (const float*)d_in[7];
    const float* edgeb = (const float*)d_in[8];
    const float* cW1[3] = {(const float*)d_in[9],  (const float*)d_in[13], (const float*)d_in[17]};
    const float* cb1[3] = {(const float*)d_in[10], (const float*)d_in[14], (const float*)d_in[18]};
    const float* cW2[3] = {(const float*)d_in[11], (const float*)d_in[15], (const float*)d_in[19]};
    const float* cb2[3] = {(const float*)d_in[12], (const float*)d_in[16], (const float*)d_in[20]};
    const float* d1W = (const float*)d_in[21];
    const float* d1b = (const float*)d_in[22];
    const float* d2W = (const float*)d_in[23];
    const float* d2b = (const float*)d_in[24];
    const float* oW  = (const float*)d_in[25];
    const float* ob  = (const float*)d_in[26];

    const int* src = eidx;
    const int* dst = eidx + N_EDGES;

    float* ws    = (float*)d_ws;
    float* h     = ws;                                  // N*64
    float* denom = h     + (size_t)N_NODES * HD;        // N*64
    float* num   = denom + (size_t)N_NODES * HD;        // N*64 (contiguous w/ denom)
    float* gsum  = num   + (size_t)N_NODES * HD;        // G*64
    float* gcnt  = gsum  + (size_t)N_GRAPHS * HD;       // G   (contiguous w/ gsum)

    k_node_embed<<<(N_NODES * HD + 255) / 256, 256, 0, stream>>>(x, nodeW, nodeb, h);

    for (int l = 0; l < 3; l++) {
        hipMemsetAsync(denom, 0, (size_t)N_NODES * HD * 2 * sizeof(float), stream);
        k_edge_pass<<<(N_EDGES + 255) / 256, 256, 0, stream>>>(
            h, src, dst, eattr, edgeW, edgeb, denom, num);
        k_mlp<<<(N_NODES + 63) / 64, 256, 0, stream>>>(
            h, denom, num, cW1[l], cb1[l], cW2[l], cb2[l], h);
    }

    hipMemsetAsync(gsum, 0, (size_t)(N_GRAPHS * HD + N_GRAPHS) * sizeof(float), stream);
    k_pool<<<(N_NODES * HD + 255) / 256, 256, 0, stream>>>(h, batch, gsum, gcnt);
    k_head<<<N_GRAPHS, 64, 0, stream>>>(gsum, gcnt, gattr,
                                        d1W, d1b, d2W, d2b, oW, ob,
                                        (float*)d_out);
}

// Round 3
// 1726.864 us; speedup vs baseline: 18.3719x; 18.3719x over previous
//
#include <hip/hip_runtime.h>
#include <hip/hip_bf16.h>

#define N_NODES 100000
#define N_EDGES 1600000
#define N_GRAPHS 1024
#define F_NODE 16
#define F_EDGE 8
#define F_GRAPH 10
#define HD 64
#define HD2 128
#define GEN_EPS 1e-7f

// h[n][f] = node_b[f] + sum_k x[n][k]*node_W[k][f]
__global__ void __launch_bounds__(256) k_node_embed(
        const float* __restrict__ x, const float* __restrict__ W,
        const float* __restrict__ b, float* __restrict__ h) {
    __shared__ float sW[F_NODE * HD];
    __shared__ float sb[HD];
    for (int i = threadIdx.x; i < F_NODE * HD; i += 256) sW[i] = W[i];
    if (threadIdx.x < HD) sb[threadIdx.x] = b[threadIdx.x];
    __syncthreads();
    int t = blockIdx.x * 256 + threadIdx.x;
    if (t >= N_NODES * HD) return;
    int n = t >> 6, f = t & 63;
    const float* xr = x + (size_t)n * F_NODE;
    float acc = sb[f];
#pragma unroll
    for (int k = 0; k < F_NODE; k++) acc += xr[k] * sW[k * HD + f];
    h[t] = acc;
}

// ---- CSR build (once per launch, reused by all 3 conv layers) ----
__global__ void __launch_bounds__(256) k_hist(
        const int* __restrict__ dst, int* __restrict__ deg) {
    int e = blockIdx.x * 256 + threadIdx.x;
    if (e >= N_EDGES) return;
    atomicAdd(&deg[dst[e]], 1);
}

// Exclusive scan of deg[0..N) -> off[0..N], single block of 1024 threads.
__global__ void __launch_bounds__(1024) k_scan(
        const int* __restrict__ deg, int* __restrict__ off) {
    __shared__ int part[1024];
    const int CH = (N_NODES + 1023) / 1024;
    int t = threadIdx.x;
    int base = t * CH;
    int s = 0;
    for (int i = 0; i < CH; i++) {
        int idx = base + i;
        if (idx < N_NODES) s += deg[idx];
    }
    part[t] = s;
    __syncthreads();
    for (int d = 1; d < 1024; d <<= 1) {
        int v = (t >= d) ? part[t - d] : 0;
        __syncthreads();
        part[t] += v;
        __syncthreads();
    }
    int run = (t == 0) ? 0 : part[t - 1];
    for (int i = 0; i < CH; i++) {
        int idx = base + i;
        if (idx < N_NODES) {
            off[idx] = run;
            run += deg[idx];
        }
    }
    if (t == 1023) off[N_NODES] = run;
}

__global__ void __launch_bounds__(256) k_scatter(
        const int* __restrict__ src, const int* __restrict__ dst,
        int* __restrict__ cursor, int* __restrict__ perm,
        int* __restrict__ psrc) {
    int e = blockIdx.x * 256 + threadIdx.x;
    if (e >= N_EDGES) return;
    int d = dst[e];
    int pos = atomicAdd(&cursor[d], 1);
    perm[pos] = e;
    psrc[pos] = src[e];
}

// ---- GENConv aggregation: one wave per destination node, lane = feature.
// denom/num in registers, softmax without max-shift (msg is O(1), exp-safe),
// root add fused; one coalesced 256B store per node. NO atomics.
__global__ void __launch_bounds__(256) k_gen_agg(
        const float* __restrict__ h, const int* __restrict__ off,
        const int* __restrict__ perm, const int* __restrict__ psrc,
        const float* __restrict__ eattr,
        const float* __restrict__ eW, const float* __restrict__ eb,
        float* __restrict__ outb) {
    int n = blockIdx.x * 4 + (threadIdx.x >> 6);
    if (n >= N_NODES) return;
    int f = threadIdx.x & 63;
    float w[F_EDGE];
#pragma unroll
    for (int k = 0; k < F_EDGE; k++) w[k] = eW[k * HD + f];
    float bf = eb[f];
    int beg = off[n], end = off[n + 1];
    float den = 0.f, nm = 0.f;
    for (int i = beg; i < end; i++) {
        int e = perm[i];
        int s = psrc[i];
        const float4* ap = reinterpret_cast<const float4*>(eattr + (size_t)e * F_EDGE);
        float4 a0 = ap[0], a1 = ap[1];
        float hv = h[(size_t)s * HD + f];
        float eaf = bf + a0.x * w[0] + a0.y * w[1] + a0.z * w[2] + a0.w * w[3]
                       + a1.x * w[4] + a1.y * w[5] + a1.z * w[6] + a1.w * w[7];
        float msg = fmaxf(hv + eaf, 0.f) + GEN_EPS;
        float ev = __expf(msg);
        den += ev;
        nm += msg * ev;
    }
    size_t idx = (size_t)n * HD + f;
    outb[idx] = h[idx] + nm / fmaxf(den, 1e-16f);
}

// Fused GENConv MLP: hid = relu(in@W1+b1) (LDS); h' = relu(hid@W2+b2).
// 64 nodes per block, 4 at a time. LDS ~68 KB -> 2 blocks/CU.
__global__ void __launch_bounds__(256) k_mlp(
        const float* __restrict__ inb,
        const float* __restrict__ W1, const float* __restrict__ b1,
        const float* __restrict__ W2, const float* __restrict__ b2,
        float* __restrict__ hout) {
    __shared__ float sW1[HD * HD2];   // 32 KB
    __shared__ float sW2[HD2 * HD];   // 32 KB
    __shared__ float sb1[HD2];
    __shared__ float sb2[HD];
    __shared__ float sOut[4][HD];
    __shared__ float sHid[4][HD2];
    for (int i = threadIdx.x; i < HD * HD2; i += 256) {
        sW1[i] = W1[i];
        sW2[i] = W2[i];
    }
    if (threadIdx.x < HD2) sb1[threadIdx.x] = b1[threadIdx.x];
    if (threadIdx.x < HD) sb2[threadIdx.x] = b2[threadIdx.x];
    __syncthreads();
    int block_n0 = blockIdx.x * 64;
    for (int it = 0; it < 16; it++) {
        int n0 = block_n0 + it * 4;
        {
            int nl = threadIdx.x >> 6, f = threadIdx.x & 63;
            int n = n0 + nl;
            sOut[nl][f] = (n < N_NODES) ? inb[(size_t)n * HD + f] : 0.f;
        }
        __syncthreads();
        {
            int j = threadIdx.x & 127;
            int nlb = threadIdx.x >> 7;
#pragma unroll
            for (int rep = 0; rep < 2; rep++) {
                int nl = nlb + rep * 2;
                float acc = sb1[j];
#pragma unroll
                for (int f = 0; f < HD; f++) acc += sOut[nl][f] * sW1[f * HD2 + j];
                sHid[nl][j] = fmaxf(acc, 0.f);
            }
        }
        __syncthreads();
        {
            int nl = threadIdx.x >> 6, f = threadIdx.x & 63;
            int n = n0 + nl;
            float acc = sb2[f];
#pragma unroll
            for (int jj = 0; jj < HD2; jj++) acc += sHid[nl][jj] * sW2[jj * HD + f];
            if (n < N_NODES) hout[(size_t)n * HD + f] = fmaxf(acc, 0.f);
        }
        __syncthreads();
    }
}

// batch is sorted -> graph g owns contiguous node range [gstart[g], gstart[g+1]).
__global__ void __launch_bounds__(256) k_gstart(
        const int* __restrict__ batch, int* __restrict__ gstart) {
    int g = blockIdx.x * 256 + threadIdx.x;
    if (g > N_GRAPHS) return;
    int lo = 0, hi = N_NODES;
    while (lo < hi) {
        int mid = (lo + hi) >> 1;
        if (batch[mid] < g) lo = mid + 1; else hi = mid;
    }
    gstart[g] = lo;
}

// One wave per graph, lane = feature: pooled[g][f] = mean over node range.
__global__ void __launch_bounds__(256) k_pool(
        const float* __restrict__ h, const int* __restrict__ gstart,
        float* __restrict__ pooled) {
    int g = blockIdx.x * 4 + (threadIdx.x >> 6);
    if (g >= N_GRAPHS) return;
    int f = threadIdx.x & 63;
    int b = gstart[g], e = gstart[g + 1];
    float s = 0.f;
    for (int n = b; n < e; n++) s += h[(size_t)n * HD + f];
    float cnt = fmaxf((float)(e - b), 1.f);
    pooled[(size_t)g * HD + f] = s / cnt;
}

__global__ void __launch_bounds__(64) k_head(
        const float* __restrict__ pooled, const float* __restrict__ gattr,
        const float* __restrict__ d1W, const float* __restrict__ d1b,
        const float* __restrict__ d2W, const float* __restrict__ d2b,
        const float* __restrict__ oW, const float* __restrict__ ob,
        float* __restrict__ out) {
    int g = blockIdx.x;
    __shared__ float si[HD + F_GRAPH];
    __shared__ float s1[32], s2[32];
    int t = threadIdx.x;
    if (t < HD) si[t] = pooled[(size_t)g * HD + t];
    if (t < F_GRAPH) si[HD + t] = gattr[(size_t)g * F_GRAPH + t];
    __syncthreads();
    if (t < 32) {
        float acc = d1b[t];
        for (int i = 0; i < HD + F_GRAPH; i++) acc += si[i] * d1W[i * 32 + t];
        s1[t] = fmaxf(acc, 0.f);
    }
    __syncthreads();
    if (t < 32) {
        float acc = d2b[t];
        for (int i = 0; i < 32; i++) acc += s1[i] * d2W[i * 32 + t];
        s2[t] = fmaxf(acc, 0.f);
    }
    __syncthreads();
    if (t == 0) {
        float acc = ob[0];
        for (int i = 0; i < 32; i++) acc += s2[i] * oW[i];
        out[g] = 1.f / (1.f + __expf(-acc));
    }
}

extern "C" void kernel_launch(void* const* d_in, const int* in_sizes, int n_in,
                              void* d_out, int out_size, void* d_ws, size_t ws_size,
                              hipStream_t stream) {
    const float* x     = (const float*)d_in[0];
    const float* eattr = (const float*)d_in[1];
    const float* gattr = (const float*)d_in[2];
    const int*   eidx  = (const int*)d_in[3];
    const int*   batch = (const int*)d_in[4];
    const float* nodeW = (const float*)d_in[5];
    const float* nodeb = (const float*)d_in[6];
    const float* edgeW = (const float*)d_in[7];
    const float* edgeb = (const float*)d_in[8];
    const float* cW1[3] = {(const float*)d_in[9],  (const float*)d_in[13], (const float*)d_in[17]};
    const float* cb1[3] = {(const float*)d_in[10], (const float*)d_in[14], (const float*)d_in[18]};
    const float* cW2[3] = {(const float*)d_in[11], (const float*)d_in[15], (const float*)d_in[19]};
    const float* cb2[3] = {(const float*)d_in[12], (const float*)d_in[16], (const float*)d_in[20]};
    const float* d1W = (const float*)d_in[21];
    const float* d1b = (const float*)d_in[22];
    const float* d2W = (const float*)d_in[23];
    const float* d2b = (const float*)d_in[24];
    const float* oW  = (const float*)d_in[25];
    const float* ob  = (const float*)d_in[26];

    const int* src = eidx;
    const int* dst = eidx + N_EDGES;

    // workspace layout
    char* p = (char*)d_ws;
    float* h      = (float*)p; p += (size_t)N_NODES * HD * 4;     // 25.6 MB
    float* outb   = (float*)p; p += (size_t)N_NODES * HD * 4;     // 25.6 MB
    float* pooled = (float*)p; p += (size_t)N_GRAPHS * HD * 4;
    int*   off    = (int*)p;   p += (size_t)(N_NODES + 1) * 4;
    int*   cursor = (int*)p;   p += (size_t)N_NODES * 4;
    int*   gstart = (int*)p;   p += (size_t)(N_GRAPHS + 1) * 4;
    int*   perm   = (int*)p;   p += (size_t)N_EDGES * 4;          // 6.4 MB
    int*   psrc   = (int*)p;   p += (size_t)N_EDGES * 4;          // 6.4 MB

    const int EB = (N_EDGES + 255) / 256;

    k_node_embed<<<(N_NODES * HD + 255) / 256, 256, 0, stream>>>(x, nodeW, nodeb, h);

    // CSR build
    hipMemsetAsync(cursor, 0, (size_t)N_NODES * 4, stream);
    k_hist<<<EB, 256, 0, stream>>>(dst, cursor);
    k_scan<<<1, 1024, 0, stream>>>(cursor, off);
    hipMemcpyAsync(cursor, off, (size_t)N_NODES * 4, hipMemcpyDeviceToDevice, stream);
    k_scatter<<<EB, 256, 0, stream>>>(src, dst, cursor, perm, psrc);

    for (int l = 0; l < 3; l++) {
        k_gen_agg<<<(N_NODES + 3) / 4, 256, 0, stream>>>(
            h, off, perm, psrc, eattr, edgeW, edgeb, outb);
        k_mlp<<<(N_NODES + 63) / 64, 256, 0, stream>>>(
            outb, cW1[l], cb1[l], cW2[l], cb2[l], h);
    }

    k_gstart<<<(N_GRAPHS + 256) / 256, 256, 0, stream>>>(batch, gstart);
    k_pool<<<(N_GRAPHS + 3) / 4, 256, 0, stream>>>(h, gstart, pooled);
    k_head<<<N_GRAPHS, 64, 0, stream>>>(pooled, gattr,
                                        d1W, d1b, d2W, d2b, oW, ob,
                                        (float*)d_out);
}

// Round 4
// 1558.022 us; speedup vs baseline: 20.3628x; 1.1084x over previous
//
#include <hip/hip_runtime.h>
#include <hip/hip_bf16.h>

#define N_NODES 100000
#define N_EDGES 1600000
#define N_GRAPHS 1024
#define F_NODE 16
#define F_EDGE 8
#define F_GRAPH 10
#define HD 64
#define HD2 128
#define GEN_EPS 1e-7f

// h[n][f] = node_b[f] + sum_k x[n][k]*node_W[k][f]
__global__ void __launch_bounds__(256) k_node_embed(
        const float* __restrict__ x, const float* __restrict__ W,
        const float* __restrict__ b, float* __restrict__ h) {
    __shared__ float sW[F_NODE * HD];
    __shared__ float sb[HD];
    for (int i = threadIdx.x; i < F_NODE * HD; i += 256) sW[i] = W[i];
    if (threadIdx.x < HD) sb[threadIdx.x] = b[threadIdx.x];
    __syncthreads();
    int t = blockIdx.x * 256 + threadIdx.x;
    if (t >= N_NODES * HD) return;
    int n = t >> 6, f = t & 63;
    const float* xr = x + (size_t)n * F_NODE;
    float acc = sb[f];
#pragma unroll
    for (int k = 0; k < F_NODE; k++) acc += xr[k] * sW[k * HD + f];
    h[t] = acc;
}

// ---- CSR build (once per launch, reused by all 3 conv layers) ----
__global__ void __launch_bounds__(256) k_hist(
        const int* __restrict__ dst, int* __restrict__ deg) {
    int e = blockIdx.x * 256 + threadIdx.x;
    if (e >= N_EDGES) return;
    atomicAdd(&deg[dst[e]], 1);
}

// Exclusive scan of deg[0..N) -> off[0..N], single block of 1024 threads.
__global__ void __launch_bounds__(1024) k_scan(
        const int* __restrict__ deg, int* __restrict__ off) {
    __shared__ int part[1024];
    const int CH = (N_NODES + 1023) / 1024;
    int t = threadIdx.x;
    int base = t * CH;
    int s = 0;
    for (int i = 0; i < CH; i++) {
        int idx = base + i;
        if (idx < N_NODES) s += deg[idx];
    }
    part[t] = s;
    __syncthreads();
    for (int d = 1; d < 1024; d <<= 1) {
        int v = (t >= d) ? part[t - d] : 0;
        __syncthreads();
        part[t] += v;
        __syncthreads();
    }
    int run = (t == 0) ? 0 : part[t - 1];
    for (int i = 0; i < CH; i++) {
        int idx = base + i;
        if (idx < N_NODES) {
            off[idx] = run;
            run += deg[idx];
        }
    }
    if (t == 1023) off[N_NODES] = run;
}

__global__ void __launch_bounds__(256) k_scatter(
        const int* __restrict__ src, const int* __restrict__ dst,
        int* __restrict__ cursor, int* __restrict__ perm,
        int* __restrict__ psrc) {
    int e = blockIdx.x * 256 + threadIdx.x;
    if (e >= N_EDGES) return;
    int d = dst[e];
    int pos = atomicAdd(&cursor[d], 1);
    perm[pos] = e;
    psrc[pos] = src[e];
}

// Gather eattr rows into CSR (perm) order so agg layers stream them.
// 8 lanes per edge: lane c reads eattr[perm[i]*8+c] (coalesced 32B chunks),
// writes ea_lin[i*8+c] (perfectly coalesced).
__global__ void __launch_bounds__(256) k_gather_ea(
        const int* __restrict__ perm, const float* __restrict__ eattr,
        float* __restrict__ ea_lin) {
    long long t = (long long)blockIdx.x * 256 + threadIdx.x;
    if (t >= (long long)N_EDGES * F_EDGE) return;
    int i = (int)(t >> 3), c = (int)(t & 7);
    int e = perm[i];
    ea_lin[(size_t)i * F_EDGE + c] = eattr[(size_t)e * F_EDGE + c];
}

// ---- GENConv aggregation: one wave per destination node, lane = feature.
// psrc + ea_lin stream sequentially (CSR order); h rows gathered (L2/L3).
// Edge loop unrolled x4 with independent loads in flight. NO atomics.
__global__ void __launch_bounds__(256) k_gen_agg(
        const float* __restrict__ h, const int* __restrict__ off,
        const int* __restrict__ psrc, const float* __restrict__ ea_lin,
        const float* __restrict__ eW, const float* __restrict__ eb,
        float* __restrict__ outb) {
    int n = blockIdx.x * 4 + (threadIdx.x >> 6);
    if (n >= N_NODES) return;
    int f = threadIdx.x & 63;
    float w[F_EDGE];
#pragma unroll
    for (int k = 0; k < F_EDGE; k++) w[k] = eW[k * HD + f];
    float bf = eb[f];
    int beg = off[n], end = off[n + 1];
    float den = 0.f, nm = 0.f;
    int i = beg;
    for (; i + 4 <= end; i += 4) {
        int s0 = psrc[i], s1 = psrc[i + 1], s2 = psrc[i + 2], s3 = psrc[i + 3];
        const float4* ap = reinterpret_cast<const float4*>(ea_lin + (size_t)i * F_EDGE);
        float4 a0 = ap[0], a1 = ap[1];
        float4 b0 = ap[2], b1 = ap[3];
        float4 c0 = ap[4], c1 = ap[5];
        float4 d0 = ap[6], d1 = ap[7];
        float hv0 = h[(size_t)s0 * HD + f];
        float hv1 = h[(size_t)s1 * HD + f];
        float hv2 = h[(size_t)s2 * HD + f];
        float hv3 = h[(size_t)s3 * HD + f];
        float ea0 = bf + a0.x * w[0] + a0.y * w[1] + a0.z * w[2] + a0.w * w[3]
                       + a1.x * w[4] + a1.y * w[5] + a1.z * w[6] + a1.w * w[7];
        float ea1 = bf + b0.x * w[0] + b0.y * w[1] + b0.z * w[2] + b0.w * w[3]
                       + b1.x * w[4] + b1.y * w[5] + b1.z * w[6] + b1.w * w[7];
        float ea2 = bf + c0.x * w[0] + c0.y * w[1] + c0.z * w[2] + c0.w * w[3]
                       + c1.x * w[4] + c1.y * w[5] + c1.z * w[6] + c1.w * w[7];
        float ea3 = bf + d0.x * w[0] + d0.y * w[1] + d0.z * w[2] + d0.w * w[3]
                       + d1.x * w[4] + d1.y * w[5] + d1.z * w[6] + d1.w * w[7];
        float m0 = fmaxf(hv0 + ea0, 0.f) + GEN_EPS;
        float m1 = fmaxf(hv1 + ea1, 0.f) + GEN_EPS;
        float m2 = fmaxf(hv2 + ea2, 0.f) + GEN_EPS;
        float m3 = fmaxf(hv3 + ea3, 0.f) + GEN_EPS;
        float e0 = __expf(m0), e1 = __expf(m1), e2 = __expf(m2), e3 = __expf(m3);
        den += e0 + e1 + e2 + e3;
        nm += m0 * e0 + m1 * e1 + m2 * e2 + m3 * e3;
    }
    for (; i < end; i++) {
        int s = psrc[i];
        const float4* ap = reinterpret_cast<const float4*>(ea_lin + (size_t)i * F_EDGE);
        float4 a0 = ap[0], a1 = ap[1];
        float hv = h[(size_t)s * HD + f];
        float eaf = bf + a0.x * w[0] + a0.y * w[1] + a0.z * w[2] + a0.w * w[3]
                       + a1.x * w[4] + a1.y * w[5] + a1.z * w[6] + a1.w * w[7];
        float msg = fmaxf(hv + eaf, 0.f) + GEN_EPS;
        float ev = __expf(msg);
        den += ev;
        nm += msg * ev;
    }
    size_t idx = (size_t)n * HD + f;
    outb[idx] = h[idx] + nm / fmaxf(den, 1e-16f);
}

// Fused GENConv MLP: hid = relu(in@W1+b1) (LDS); h' = relu(hid@W2+b2).
// 64 nodes per block, 4 at a time. LDS ~68 KB -> 2 blocks/CU.
__global__ void __launch_bounds__(256) k_mlp(
        const float* __restrict__ inb,
        const float* __restrict__ W1, const float* __restrict__ b1,
        const float* __restrict__ W2, const float* __restrict__ b2,
        float* __restrict__ hout) {
    __shared__ float sW1[HD * HD2];   // 32 KB
    __shared__ float sW2[HD2 * HD];   // 32 KB
    __shared__ float sb1[HD2];
    __shared__ float sb2[HD];
    __shared__ float sOut[4][HD];
    __shared__ float sHid[4][HD2];
    for (int i = threadIdx.x; i < HD * HD2; i += 256) {
        sW1[i] = W1[i];
        sW2[i] = W2[i];
    }
    if (threadIdx.x < HD2) sb1[threadIdx.x] = b1[threadIdx.x];
    if (threadIdx.x < HD) sb2[threadIdx.x] = b2[threadIdx.x];
    __syncthreads();
    int block_n0 = blockIdx.x * 64;
    for (int it = 0; it < 16; it++) {
        int n0 = block_n0 + it * 4;
        {
            int nl = threadIdx.x >> 6, f = threadIdx.x & 63;
            int n = n0 + nl;
            sOut[nl][f] = (n < N_NODES) ? inb[(size_t)n * HD + f] : 0.f;
        }
        __syncthreads();
        {
            int j = threadIdx.x & 127;
            int nlb = threadIdx.x >> 7;
#pragma unroll
            for (int rep = 0; rep < 2; rep++) {
                int nl = nlb + rep * 2;
                float acc = sb1[j];
#pragma unroll
                for (int f = 0; f < HD; f++) acc += sOut[nl][f] * sW1[f * HD2 + j];
                sHid[nl][j] = fmaxf(acc, 0.f);
            }
        }
        __syncthreads();
        {
            int nl = threadIdx.x >> 6, f = threadIdx.x & 63;
            int n = n0 + nl;
            float acc = sb2[f];
#pragma unroll
            for (int jj = 0; jj < HD2; jj++) acc += sHid[nl][jj] * sW2[jj * HD + f];
            if (n < N_NODES) hout[(size_t)n * HD + f] = fmaxf(acc, 0.f);
        }
        __syncthreads();
    }
}

// batch is sorted -> graph g owns contiguous node range [gstart[g], gstart[g+1]).
__global__ void __launch_bounds__(256) k_gstart(
        const int* __restrict__ batch, int* __restrict__ gstart) {
    int g = blockIdx.x * 256 + threadIdx.x;
    if (g > N_GRAPHS) return;
    int lo = 0, hi = N_NODES;
    while (lo < hi) {
        int mid = (lo + hi) >> 1;
        if (batch[mid] < g) lo = mid + 1; else hi = mid;
    }
    gstart[g] = lo;
}

// One wave per graph, lane = feature: pooled[g][f] = mean over node range.
__global__ void __launch_bounds__(256) k_pool(
        const float* __restrict__ h, const int* __restrict__ gstart,
        float* __restrict__ pooled) {
    int g = blockIdx.x * 4 + (threadIdx.x >> 6);
    if (g >= N_GRAPHS) return;
    int f = threadIdx.x & 63;
    int b = gstart[g], e = gstart[g + 1];
    float s = 0.f;
    for (int n = b; n < e; n++) s += h[(size_t)n * HD + f];
    float cnt = fmaxf((float)(e - b), 1.f);
    pooled[(size_t)g * HD + f] = s / cnt;
}

__global__ void __launch_bounds__(64) k_head(
        const float* __restrict__ pooled, const float* __restrict__ gattr,
        const float* __restrict__ d1W, const float* __restrict__ d1b,
        const float* __restrict__ d2W, const float* __restrict__ d2b,
        const float* __restrict__ oW, const float* __restrict__ ob,
        float* __restrict__ out) {
    int g = blockIdx.x;
    __shared__ float si[HD + F_GRAPH];
    __shared__ float s1[32], s2[32];
    int t = threadIdx.x;
    if (t < HD) si[t] = pooled[(size_t)g * HD + t];
    if (t < F_GRAPH) si[HD + t] = gattr[(size_t)g * F_GRAPH + t];
    __syncthreads();
    if (t < 32) {
        float acc = d1b[t];
        for (int i = 0; i < HD + F_GRAPH; i++) acc += si[i] * d1W[i * 32 + t];
        s1[t] = fmaxf(acc, 0.f);
    }
    __syncthreads();
    if (t < 32) {
        float acc = d2b[t];
        for (int i = 0; i < 32; i++) acc += s1[i] * d2W[i * 32 + t];
        s2[t] = fmaxf(acc, 0.f);
    }
    __syncthreads();
    if (t == 0) {
        float acc = ob[0];
        for (int i = 0; i < 32; i++) acc += s2[i] * oW[i];
        out[g] = 1.f / (1.f + __expf(-acc));
    }
}

extern "C" void kernel_launch(void* const* d_in, const int* in_sizes, int n_in,
                              void* d_out, int out_size, void* d_ws, size_t ws_size,
                              hipStream_t stream) {
    const float* x     = (const float*)d_in[0];
    const float* eattr = (const float*)d_in[1];
    const float* gattr = (const float*)d_in[2];
    const int*   eidx  = (const int*)d_in[3];
    const int*   batch = (const int*)d_in[4];
    const float* nodeW = (const float*)d_in[5];
    const float* nodeb = (const float*)d_in[6];
    const float* edgeW = (const float*)d_in[7];
    const float* edgeb = (const float*)d_in[8];
    const float* cW1[3] = {(const float*)d_in[9],  (const float*)d_in[13], (const float*)d_in[17]};
    const float* cb1[3] = {(const float*)d_in[10], (const float*)d_in[14], (const float*)d_in[18]};
    const float* cW2[3] = {(const float*)d_in[11], (const float*)d_in[15], (const float*)d_in[19]};
    const float* cb2[3] = {(const float*)d_in[12], (const float*)d_in[16], (const float*)d_in[20]};
    const float* d1W = (const float*)d_in[21];
    const float* d1b = (const float*)d_in[22];
    const float* d2W = (const float*)d_in[23];
    const float* d2b = (const float*)d_in[24];
    const float* oW  = (const float*)d_in[25];
    const float* ob  = (const float*)d_in[26];

    const int* src = eidx;
    const int* dst = eidx + N_EDGES;

    // workspace layout
    char* p = (char*)d_ws;
    float* h      = (float*)p; p += (size_t)N_NODES * HD * 4;       // 25.6 MB
    float* outb   = (float*)p; p += (size_t)N_NODES * HD * 4;       // 25.6 MB
    float* ea_lin = (float*)p; p += (size_t)N_EDGES * F_EDGE * 4;   // 51.2 MB
    float* pooled = (float*)p; p += (size_t)N_GRAPHS * HD * 4;
    int*   off    = (int*)p;   p += (size_t)(N_NODES + 1) * 4;
    int*   cursor = (int*)p;   p += (size_t)N_NODES * 4;
    int*   gstart = (int*)p;   p += (size_t)(N_GRAPHS + 1) * 4;
    int*   perm   = (int*)p;   p += (size_t)N_EDGES * 4;            // 6.4 MB
    int*   psrc   = (int*)p;   p += (size_t)N_EDGES * 4;            // 6.4 MB

    const int EB = (N_EDGES + 255) / 256;

    k_node_embed<<<(N_NODES * HD + 255) / 256, 256, 0, stream>>>(x, nodeW, nodeb, h);

    // CSR build
    hipMemsetAsync(cursor, 0, (size_t)N_NODES * 4, stream);
    k_hist<<<EB, 256, 0, stream>>>(dst, cursor);
    k_scan<<<1, 1024, 0, stream>>>(cursor, off);
    hipMemcpyAsync(cursor, off, (size_t)N_NODES * 4, hipMemcpyDeviceToDevice, stream);
    k_scatter<<<EB, 256, 0, stream>>>(src, dst, cursor, perm, psrc);
    k_gather_ea<<<(int)(((long long)N_EDGES * F_EDGE + 255) / 256), 256, 0, stream>>>(
        perm, eattr, ea_lin);

    for (int l = 0; l < 3; l++) {
        k_gen_agg<<<(N_NODES + 3) / 4, 256, 0, stream>>>(
            h, off, psrc, ea_lin, edgeW, edgeb, outb);
        k_mlp<<<(N_NODES + 63) / 64, 256, 0, stream>>>(
            outb, cW1[l], cb1[l], cW2[l], cb2[l], h);
    }

    k_gstart<<<(N_GRAPHS + 256) / 256, 256, 0, stream>>>(batch, gstart);
    k_pool<<<(N_GRAPHS + 3) / 4, 256, 0, stream>>>(h, gstart, pooled);
    k_head<<<N_GRAPHS, 64, 0, stream>>>(pooled, gattr,
                                        d1W, d1b, d2W, d2b, oW, ob,
                                        (float*)d_out);
}

// Round 5
// 1189.478 us; speedup vs baseline: 26.6720x; 1.3098x over previous
//
#include <hip/hip_runtime.h>
#include <hip/hip_bf16.h>

#define N_NODES 100000
#define N_EDGES 1600000
#define N_GRAPHS 1024
#define F_NODE 16
#define F_EDGE 8
#define F_GRAPH 10
#define HD 64
#define HD2 128
#define GEN_EPS 1e-7f

// h[n][f] = node_b[f] + sum_k x[n][k]*node_W[k][f]
__global__ void __launch_bounds__(256) k_node_embed(
        const float* __restrict__ x, const float* __restrict__ W,
        const float* __restrict__ b, float* __restrict__ h) {
    __shared__ float sW[F_NODE * HD];
    __shared__ float sb[HD];
    for (int i = threadIdx.x; i < F_NODE * HD; i += 256) sW[i] = W[i];
    if (threadIdx.x < HD) sb[threadIdx.x] = b[threadIdx.x];
    __syncthreads();
    int t = blockIdx.x * 256 + threadIdx.x;
    if (t >= N_NODES * HD) return;
    int n = t >> 6, f = t & 63;
    const float* xr = x + (size_t)n * F_NODE;
    float acc = sb[f];
#pragma unroll
    for (int k = 0; k < F_NODE; k++) acc += xr[k] * sW[k * HD + f];
    h[t] = acc;
}

// ---- CSR build (once per launch, reused by all 3 conv layers) ----
__global__ void __launch_bounds__(256) k_hist(
        const int* __restrict__ dst, int* __restrict__ deg) {
    int e = blockIdx.x * 256 + threadIdx.x;
    if (e >= N_EDGES) return;
    atomicAdd(&deg[dst[e]], 1);
}

// Exclusive scan of deg[0..N) -> off[0..N], single block of 1024 threads.
__global__ void __launch_bounds__(1024) k_scan(
        const int* __restrict__ deg, int* __restrict__ off) {
    __shared__ int part[1024];
    const int CH = (N_NODES + 1023) / 1024;
    int t = threadIdx.x;
    int base = t * CH;
    int s = 0;
    for (int i = 0; i < CH; i++) {
        int idx = base + i;
        if (idx < N_NODES) s += deg[idx];
    }
    part[t] = s;
    __syncthreads();
    for (int d = 1; d < 1024; d <<= 1) {
        int v = (t >= d) ? part[t - d] : 0;
        __syncthreads();
        part[t] += v;
        __syncthreads();
    }
    int run = (t == 0) ? 0 : part[t - 1];
    for (int i = 0; i < CH; i++) {
        int idx = base + i;
        if (idx < N_NODES) {
            off[idx] = run;
            run += deg[idx];
        }
    }
    if (t == 1023) off[N_NODES] = run;
}

__global__ void __launch_bounds__(256) k_scatter(
        const int* __restrict__ src, const int* __restrict__ dst,
        int* __restrict__ cursor, int* __restrict__ perm,
        int* __restrict__ psrc) {
    int e = blockIdx.x * 256 + threadIdx.x;
    if (e >= N_EDGES) return;
    int d = dst[e];
    int pos = atomicAdd(&cursor[d], 1);
    perm[pos] = e;
    psrc[pos] = src[e];
}

// Gather eattr rows into CSR (perm) order so agg layers stream them.
__global__ void __launch_bounds__(256) k_gather_ea(
        const int* __restrict__ perm, const float* __restrict__ eattr,
        float* __restrict__ ea_lin) {
    long long t = (long long)blockIdx.x * 256 + threadIdx.x;
    if (t >= (long long)N_EDGES * F_EDGE) return;
    int i = (int)(t >> 3), c = (int)(t & 7);
    int e = perm[i];
    ea_lin[(size_t)i * F_EDGE + c] = eattr[(size_t)e * F_EDGE + c];
}

// ---- GENConv aggregation: one wave per destination node, lane = feature.
__global__ void __launch_bounds__(256) k_gen_agg(
        const float* __restrict__ h, const int* __restrict__ off,
        const int* __restrict__ psrc, const float* __restrict__ ea_lin,
        const float* __restrict__ eW, const float* __restrict__ eb,
        float* __restrict__ outb) {
    int n = blockIdx.x * 4 + (threadIdx.x >> 6);
    if (n >= N_NODES) return;
    int f = threadIdx.x & 63;
    float w[F_EDGE];
#pragma unroll
    for (int k = 0; k < F_EDGE; k++) w[k] = eW[k * HD + f];
    float bf = eb[f];
    int beg = off[n], end = off[n + 1];
    float den = 0.f, nm = 0.f;
    int i = beg;
    for (; i + 4 <= end; i += 4) {
        int s0 = psrc[i], s1 = psrc[i + 1], s2 = psrc[i + 2], s3 = psrc[i + 3];
        const float4* ap = reinterpret_cast<const float4*>(ea_lin + (size_t)i * F_EDGE);
        float4 a0 = ap[0], a1 = ap[1];
        float4 b0 = ap[2], b1 = ap[3];
        float4 c0 = ap[4], c1 = ap[5];
        float4 d0 = ap[6], d1 = ap[7];
        float hv0 = h[(size_t)s0 * HD + f];
        float hv1 = h[(size_t)s1 * HD + f];
        float hv2 = h[(size_t)s2 * HD + f];
        float hv3 = h[(size_t)s3 * HD + f];
        float ea0 = bf + a0.x * w[0] + a0.y * w[1] + a0.z * w[2] + a0.w * w[3]
                       + a1.x * w[4] + a1.y * w[5] + a1.z * w[6] + a1.w * w[7];
        float ea1 = bf + b0.x * w[0] + b0.y * w[1] + b0.z * w[2] + b0.w * w[3]
                       + b1.x * w[4] + b1.y * w[5] + b1.z * w[6] + b1.w * w[7];
        float ea2 = bf + c0.x * w[0] + c0.y * w[1] + c0.z * w[2] + c0.w * w[3]
                       + c1.x * w[4] + c1.y * w[5] + c1.z * w[6] + c1.w * w[7];
        float ea3 = bf + d0.x * w[0] + d0.y * w[1] + d0.z * w[2] + d0.w * w[3]
                       + d1.x * w[4] + d1.y * w[5] + d1.z * w[6] + d1.w * w[7];
        float m0 = fmaxf(hv0 + ea0, 0.f) + GEN_EPS;
        float m1 = fmaxf(hv1 + ea1, 0.f) + GEN_EPS;
        float m2 = fmaxf(hv2 + ea2, 0.f) + GEN_EPS;
        float m3 = fmaxf(hv3 + ea3, 0.f) + GEN_EPS;
        float e0 = __expf(m0), e1 = __expf(m1), e2 = __expf(m2), e3 = __expf(m3);
        den += e0 + e1 + e2 + e3;
        nm += m0 * e0 + m1 * e1 + m2 * e2 + m3 * e3;
    }
    for (; i < end; i++) {
        int s = psrc[i];
        const float4* ap = reinterpret_cast<const float4*>(ea_lin + (size_t)i * F_EDGE);
        float4 a0 = ap[0], a1 = ap[1];
        float hv = h[(size_t)s * HD + f];
        float eaf = bf + a0.x * w[0] + a0.y * w[1] + a0.z * w[2] + a0.w * w[3]
                       + a1.x * w[4] + a1.y * w[5] + a1.z * w[6] + a1.w * w[7];
        float msg = fmaxf(hv + eaf, 0.f) + GEN_EPS;
        float ev = __expf(msg);
        den += ev;
        nm += msg * ev;
    }
    size_t idx = (size_t)n * HD + f;
    outb[idx] = h[idx] + nm / fmaxf(den, 1e-16f);
}

// ---- MLP stage 1: hid[n][j] = relu(in[n][:] @ W1[:, j] + b1[j]), K=64, J=128.
// 64-node tile in LDS; thread tile 8 nodes x 4 j (register accumulators).
// LDS ~50.7 KB -> 3 blocks/CU.
__global__ void __launch_bounds__(256) k_mlp1(
        const float* __restrict__ inb,
        const float* __restrict__ W1, const float* __restrict__ b1,
        float* __restrict__ hid) {
    __shared__ float sIn[64][HD + 4];   // pad 68: bank stride 4
    __shared__ float sW1[HD * HD2];     // [f][j] row-major, 32 KB
    __shared__ float sb1[HD2];
    int tid = threadIdx.x;
    int n0 = blockIdx.x * 64;
    for (int i = tid; i < HD * HD2; i += 256) sW1[i] = W1[i];
    if (tid < HD2) sb1[tid] = b1[tid];
    // stage input tile (vector loads, coalesced)
    for (int i = tid; i < 64 * (HD / 4); i += 256) {
        int n = i >> 4, fq = i & 15;
        int gn = n0 + n;
        float4 v = (gn < N_NODES)
            ? reinterpret_cast<const float4*>(inb + (size_t)gn * HD)[fq]
            : make_float4(0.f, 0.f, 0.f, 0.f);
        sIn[n][fq * 4 + 0] = v.x; sIn[n][fq * 4 + 1] = v.y;
        sIn[n][fq * 4 + 2] = v.z; sIn[n][fq * 4 + 3] = v.w;
    }
    __syncthreads();
    int ng = tid >> 5;          // 0..7  -> 8 nodes each
    int jg = tid & 31;          // 0..31 -> 4 j each
    int nb = ng * 8, jb = jg * 4;
    float acc[8][4];
#pragma unroll
    for (int i = 0; i < 8; i++)
#pragma unroll
        for (int q = 0; q < 4; q++) acc[i][q] = sb1[jb + q];
#pragma unroll 4
    for (int f = 0; f < HD; f++) {
        float4 w = *reinterpret_cast<const float4*>(&sW1[f * HD2 + jb]);
        float xv[8];
#pragma unroll
        for (int i = 0; i < 8; i++) xv[i] = sIn[nb + i][f];
#pragma unroll
        for (int i = 0; i < 8; i++) {
            acc[i][0] += xv[i] * w.x;
            acc[i][1] += xv[i] * w.y;
            acc[i][2] += xv[i] * w.z;
            acc[i][3] += xv[i] * w.w;
        }
    }
#pragma unroll
    for (int i = 0; i < 8; i++) {
        int gn = n0 + nb + i;
        if (gn < N_NODES) {
            float4 o;
            o.x = fmaxf(acc[i][0], 0.f);
            o.y = fmaxf(acc[i][1], 0.f);
            o.z = fmaxf(acc[i][2], 0.f);
            o.w = fmaxf(acc[i][3], 0.f);
            *reinterpret_cast<float4*>(hid + (size_t)gn * HD2 + jb) = o;
        }
    }
}

// ---- MLP stage 2: h'[n][j] = relu(hid[n][:] @ W2[:, j] + b2[j]), K=128, J=64.
// 64-node tile; thread tile 4 nodes x 4 j. LDS ~66.8 KB -> 2 blocks/CU.
__global__ void __launch_bounds__(256) k_mlp2(
        const float* __restrict__ hid,
        const float* __restrict__ W2, const float* __restrict__ b2,
        float* __restrict__ hout) {
    __shared__ float sH[64][HD2 + 4];   // pad 132
    __shared__ float sW2[HD2 * HD];     // [f][j] row-major, 32 KB
    __shared__ float sb2[HD];
    int tid = threadIdx.x;
    int n0 = blockIdx.x * 64;
    for (int i = tid; i < HD2 * HD; i += 256) sW2[i] = W2[i];
    if (tid < HD) sb2[tid] = b2[tid];
    for (int i = tid; i < 64 * (HD2 / 4); i += 256) {
        int n = i >> 5, fq = i & 31;
        int gn = n0 + n;
        float4 v = (gn < N_NODES)
            ? reinterpret_cast<const float4*>(hid + (size_t)gn * HD2)[fq]
            : make_float4(0.f, 0.f, 0.f, 0.f);
        sH[n][fq * 4 + 0] = v.x; sH[n][fq * 4 + 1] = v.y;
        sH[n][fq * 4 + 2] = v.z; sH[n][fq * 4 + 3] = v.w;
    }
    __syncthreads();
    int ng = tid >> 4;          // 0..15 -> 4 nodes each
    int jg = tid & 15;          // 0..15 -> 4 j each
    int nb = ng * 4, jb = jg * 4;
    float acc[4][4];
#pragma unroll
    for (int i = 0; i < 4; i++)
#pragma unroll
        for (int q = 0; q < 4; q++) acc[i][q] = sb2[jb + q];
#pragma unroll 4
    for (int f = 0; f < HD2; f++) {
        float4 w = *reinterpret_cast<const float4*>(&sW2[f * HD + jb]);
        float xv[4];
#pragma unroll
        for (int i = 0; i < 4; i++) xv[i] = sH[nb + i][f];
#pragma unroll
        for (int i = 0; i < 4; i++) {
            acc[i][0] += xv[i] * w.x;
            acc[i][1] += xv[i] * w.y;
            acc[i][2] += xv[i] * w.z;
            acc[i][3] += xv[i] * w.w;
        }
    }
#pragma unroll
    for (int i = 0; i < 4; i++) {
        int gn = n0 + nb + i;
        if (gn < N_NODES) {
            float4 o;
            o.x = fmaxf(acc[i][0], 0.f);
            o.y = fmaxf(acc[i][1], 0.f);
            o.z = fmaxf(acc[i][2], 0.f);
            o.w = fmaxf(acc[i][3], 0.f);
            *reinterpret_cast<float4*>(hout + (size_t)gn * HD + jb) = o;
        }
    }
}

// batch is sorted -> graph g owns contiguous node range [gstart[g], gstart[g+1]).
__global__ void __launch_bounds__(256) k_gstart(
        const int* __restrict__ batch, int* __restrict__ gstart) {
    int g = blockIdx.x * 256 + threadIdx.x;
    if (g > N_GRAPHS) return;
    int lo = 0, hi = N_NODES;
    while (lo < hi) {
        int mid = (lo + hi) >> 1;
        if (batch[mid] < g) lo = mid + 1; else hi = mid;
    }
    gstart[g] = lo;
}

// One wave per graph, lane = feature: pooled[g][f] = mean over node range.
__global__ void __launch_bounds__(256) k_pool(
        const float* __restrict__ h, const int* __restrict__ gstart,
        float* __restrict__ pooled) {
    int g = blockIdx.x * 4 + (threadIdx.x >> 6);
    if (g >= N_GRAPHS) return;
    int f = threadIdx.x & 63;
    int b = gstart[g], e = gstart[g + 1];
    float s = 0.f;
    for (int n = b; n < e; n++) s += h[(size_t)n * HD + f];
    float cnt = fmaxf((float)(e - b), 1.f);
    pooled[(size_t)g * HD + f] = s / cnt;
}

__global__ void __launch_bounds__(64) k_head(
        const float* __restrict__ pooled, const float* __restrict__ gattr,
        const float* __restrict__ d1W, const float* __restrict__ d1b,
        const float* __restrict__ d2W, const float* __restrict__ d2b,
        const float* __restrict__ oW, const float* __restrict__ ob,
        float* __restrict__ out) {
    int g = blockIdx.x;
    __shared__ float si[HD + F_GRAPH];
    __shared__ float s1[32], s2[32];
    int t = threadIdx.x;
    if (t < HD) si[t] = pooled[(size_t)g * HD + t];
    if (t < F_GRAPH) si[HD + t] = gattr[(size_t)g * F_GRAPH + t];
    __syncthreads();
    if (t < 32) {
        float acc = d1b[t];
        for (int i = 0; i < HD + F_GRAPH; i++) acc += si[i] * d1W[i * 32 + t];
        s1[t] = fmaxf(acc, 0.f);
    }
    __syncthreads();
    if (t < 32) {
        float acc = d2b[t];
        for (int i = 0; i < 32; i++) acc += s1[i] * d2W[i * 32 + t];
        s2[t] = fmaxf(acc, 0.f);
    }
    __syncthreads();
    if (t == 0) {
        float acc = ob[0];
        for (int i = 0; i < 32; i++) acc += s2[i] * oW[i];
        out[g] = 1.f / (1.f + __expf(-acc));
    }
}

extern "C" void kernel_launch(void* const* d_in, const int* in_sizes, int n_in,
                              void* d_out, int out_size, void* d_ws, size_t ws_size,
                              hipStream_t stream) {
    const float* x     = (const float*)d_in[0];
    const float* eattr = (const float*)d_in[1];
    const float* gattr = (const float*)d_in[2];
    const int*   eidx  = (const int*)d_in[3];
    const int*   batch = (const int*)d_in[4];
    const float* nodeW = (const float*)d_in[5];
    const float* nodeb = (const float*)d_in[6];
    const float* edgeW = (const float*)d_in[7];
    const float* edgeb = (const float*)d_in[8];
    const float* cW1[3] = {(const float*)d_in[9],  (const float*)d_in[13], (const float*)d_in[17]};
    const float* cb1[3] = {(const float*)d_in[10], (const float*)d_in[14], (const float*)d_in[18]};
    const float* cW2[3] = {(const float*)d_in[11], (const float*)d_in[15], (const float*)d_in[19]};
    const float* cb2[3] = {(const float*)d_in[12], (const float*)d_in[16], (const float*)d_in[20]};
    const float* d1W = (const float*)d_in[21];
    const float* d1b = (const float*)d_in[22];
    const float* d2W = (const float*)d_in[23];
    const float* d2b = (const float*)d_in[24];
    const float* oW  = (const float*)d_in[25];
    const float* ob  = (const float*)d_in[26];

    const int* src = eidx;
    const int* dst = eidx + N_EDGES;

    // workspace layout
    char* p = (char*)d_ws;
    float* h      = (float*)p; p += (size_t)N_NODES * HD * 4;       // 25.6 MB
    float* outb   = (float*)p; p += (size_t)N_NODES * HD * 4;       // 25.6 MB
    float* hid    = (float*)p; p += (size_t)N_NODES * HD2 * 4;      // 51.2 MB
    float* ea_lin = (float*)p; p += (size_t)N_EDGES * F_EDGE * 4;   // 51.2 MB
    float* pooled = (float*)p; p += (size_t)N_GRAPHS * HD * 4;
    int*   off    = (int*)p;   p += (size_t)(N_NODES + 1) * 4;
    int*   cursor = (int*)p;   p += (size_t)N_NODES * 4;
    int*   gstart = (int*)p;   p += (size_t)(N_GRAPHS + 1) * 4;
    int*   perm   = (int*)p;   p += (size_t)N_EDGES * 4;            // 6.4 MB
    int*   psrc   = (int*)p;   p += (size_t)N_EDGES * 4;            // 6.4 MB

    const int EB = (N_EDGES + 255) / 256;
    const int NB64 = (N_NODES + 63) / 64;

    k_node_embed<<<(N_NODES * HD + 255) / 256, 256, 0, stream>>>(x, nodeW, nodeb, h);

    // CSR build
    hipMemsetAsync(cursor, 0, (size_t)N_NODES * 4, stream);
    k_hist<<<EB, 256, 0, stream>>>(dst, cursor);
    k_scan<<<1, 1024, 0, stream>>>(cursor, off);
    hipMemcpyAsync(cursor, off, (size_t)N_NODES * 4, hipMemcpyDeviceToDevice, stream);
    k_scatter<<<EB, 256, 0, stream>>>(src, dst, cursor, perm, psrc);
    k_gather_ea<<<(int)(((long long)N_EDGES * F_EDGE + 255) / 256), 256, 0, stream>>>(
        perm, eattr, ea_lin);

    for (int l = 0; l < 3; l++) {
        k_gen_agg<<<(N_NODES + 3) / 4, 256, 0, stream>>>(
            h, off, psrc, ea_lin, edgeW, edgeb, outb);
        k_mlp1<<<NB64, 256, 0, stream>>>(outb, cW1[l], cb1[l], hid);
        k_mlp2<<<NB64, 256, 0, stream>>>(hid, cW2[l], cb2[l], h);
    }

    k_gstart<<<(N_GRAPHS + 256) / 256, 256, 0, stream>>>(batch, gstart);
    k_pool<<<(N_GRAPHS + 3) / 4, 256, 0, stream>>>(h, gstart, pooled);
    k_head<<<N_GRAPHS, 64, 0, stream>>>(pooled, gattr,
                                        d1W, d1b, d2W, d2b, oW, ob,
                                        (float*)d_out);
}

// Round 6
// 892.593 us; speedup vs baseline: 35.5433x; 1.3326x over previous
//
#include <hip/hip_runtime.h>
#include <hip/hip_bf16.h>

#define N_NODES 100000
#define N_EDGES 1600000
#define N_GRAPHS 1024
#define F_NODE 16
#define F_EDGE 8
#define F_GRAPH 10
#define HD 64
#define HD2 128
#define GEN_EPS 1e-7f
#define SCAN_NBLK ((N_NODES + 255) / 256)   // 391

// h[n][f] = node_b[f] + sum_k x[n][k]*node_W[k][f]
__global__ void __launch_bounds__(256) k_node_embed(
        const float* __restrict__ x, const float* __restrict__ W,
        const float* __restrict__ b, float* __restrict__ h) {
    __shared__ float sW[F_NODE * HD];
    __shared__ float sb[HD];
    for (int i = threadIdx.x; i < F_NODE * HD; i += 256) sW[i] = W[i];
    if (threadIdx.x < HD) sb[threadIdx.x] = b[threadIdx.x];
    __syncthreads();
    int t = blockIdx.x * 256 + threadIdx.x;
    if (t >= N_NODES * HD) return;
    int n = t >> 6, f = t & 63;
    const float* xr = x + (size_t)n * F_NODE;
    float acc = sb[f];
#pragma unroll
    for (int k = 0; k < F_NODE; k++) acc += xr[k] * sW[k * HD + f];
    h[t] = acc;
}

// ---- CSR build (once per launch, reused by all 3 conv layers) ----
__global__ void __launch_bounds__(256) k_hist(
        const int* __restrict__ dst, int* __restrict__ deg) {
    int e = blockIdx.x * 256 + threadIdx.x;
    if (e >= N_EDGES) return;
    atomicAdd(&deg[dst[e]], 1);
}

// Parallel exclusive scan, 3 phases.
__global__ void __launch_bounds__(256) k_scan1(
        const int* __restrict__ deg, int* __restrict__ bsum) {
    __shared__ int red[256];
    int t = threadIdx.x;
    int g = blockIdx.x * 256 + t;
    red[t] = (g < N_NODES) ? deg[g] : 0;
    __syncthreads();
    for (int s = 128; s > 0; s >>= 1) {
        if (t < s) red[t] += red[t + s];
        __syncthreads();
    }
    if (t == 0) bsum[blockIdx.x] = red[0];
}

__global__ void __launch_bounds__(512) k_scan2(
        const int* __restrict__ bsum, int* __restrict__ bpre) {
    __shared__ int sh[512];
    int t = threadIdx.x;
    int v = (t < SCAN_NBLK) ? bsum[t] : 0;
    sh[t] = v;
    __syncthreads();
    for (int d = 1; d < 512; d <<= 1) {
        int u = (t >= d) ? sh[t - d] : 0;
        __syncthreads();
        sh[t] += u;
        __syncthreads();
    }
    if (t < SCAN_NBLK) bpre[t] = sh[t] - v;   // exclusive
}

__global__ void __launch_bounds__(256) k_scan3(
        const int* __restrict__ deg, const int* __restrict__ bpre,
        int* __restrict__ off) {
    __shared__ int sh[256];
    int t = threadIdx.x;
    int g = blockIdx.x * 256 + t;
    int v = (g < N_NODES) ? deg[g] : 0;
    sh[t] = v;
    __syncthreads();
    for (int d = 1; d < 256; d <<= 1) {
        int u = (t >= d) ? sh[t - d] : 0;
        __syncthreads();
        sh[t] += u;
        __syncthreads();
    }
    int incl = sh[t];
    int base = bpre[blockIdx.x];
    if (g < N_NODES) off[g] = base + incl - v;
    if (g == N_NODES - 1) off[N_NODES] = base + incl;
}

__global__ void __launch_bounds__(256) k_scatter(
        const int* __restrict__ src, const int* __restrict__ dst,
        int* __restrict__ cursor, int* __restrict__ perm,
        int* __restrict__ psrc) {
    int e = blockIdx.x * 256 + threadIdx.x;
    if (e >= N_EDGES) return;
    int d = dst[e];
    int pos = atomicAdd(&cursor[d], 1);
    perm[pos] = e;
    psrc[pos] = src[e];
}

// Gather eattr rows into CSR (perm) order so agg layers stream them.
__global__ void __launch_bounds__(256) k_gather_ea(
        const int* __restrict__ perm, const float* __restrict__ eattr,
        float* __restrict__ ea_lin) {
    long long t = (long long)blockIdx.x * 256 + threadIdx.x;
    if (t >= (long long)N_EDGES * F_EDGE) return;
    int i = (int)(t >> 3), c = (int)(t & 7);
    int e = perm[i];
    ea_lin[(size_t)i * F_EDGE + c] = eattr[(size_t)e * F_EDGE + c];
}

// ---- GENConv aggregation: one wave per destination node, lane = feature.
// n (and thus the edge range) is wave-uniform: readfirstlane forces the
// compiler's uniformity analysis so off/psrc/ea_lin go through the SCALAR
// path (s_load), leaving the vector pipe for the h-row gathers. Unroll x8.
__global__ void __launch_bounds__(256) k_gen_agg(
        const float* __restrict__ h, const int* __restrict__ off,
        const int* __restrict__ psrc, const float* __restrict__ ea_lin,
        const float* __restrict__ eW, const float* __restrict__ eb,
        float* __restrict__ outb) {
    int n = blockIdx.x * 4 + (threadIdx.x >> 6);
    if (n >= N_NODES) return;
    int f = threadIdx.x & 63;
    float w[F_EDGE];
#pragma unroll
    for (int k = 0; k < F_EDGE; k++) w[k] = eW[k * HD + f];
    float bf = eb[f];
    int nu = __builtin_amdgcn_readfirstlane(n);
    int beg = off[nu], end = off[nu + 1];
    float den = 0.f, nm = 0.f;
    int i = beg;
    for (; i + 8 <= end; i += 8) {
        int s[8];
#pragma unroll
        for (int u = 0; u < 8; u++) s[u] = psrc[i + u];
        float hv[8];
#pragma unroll
        for (int u = 0; u < 8; u++) hv[u] = h[(size_t)s[u] * HD + f];
#pragma unroll
        for (int u = 0; u < 8; u++) {
            const float4* ap = reinterpret_cast<const float4*>(
                ea_lin + (size_t)(i + u) * F_EDGE);
            float4 a0 = ap[0], a1 = ap[1];
            float ea = bf + a0.x * w[0] + a0.y * w[1] + a0.z * w[2] + a0.w * w[3]
                          + a1.x * w[4] + a1.y * w[5] + a1.z * w[6] + a1.w * w[7];
            float m = fmaxf(hv[u] + ea, 0.f) + GEN_EPS;
            float ev = __expf(m);
            den += ev;
            nm += m * ev;
        }
    }
    for (; i < end; i++) {
        int s = psrc[i];
        const float4* ap = reinterpret_cast<const float4*>(
            ea_lin + (size_t)i * F_EDGE);
        float4 a0 = ap[0], a1 = ap[1];
        float hv = h[(size_t)s * HD + f];
        float ea = bf + a0.x * w[0] + a0.y * w[1] + a0.z * w[2] + a0.w * w[3]
                      + a1.x * w[4] + a1.y * w[5] + a1.z * w[6] + a1.w * w[7];
        float m = fmaxf(hv + ea, 0.f) + GEN_EPS;
        float ev = __expf(m);
        den += ev;
        nm += m * ev;
    }
    size_t idx = (size_t)n * HD + f;
    outb[idx] = h[idx] + nm / fmaxf(den, 1e-16f);
}

// ---- MLP stage 1: hid[n][j] = relu(in[n][:] @ W1[:, j] + b1[j]), K=64, J=128.
__global__ void __launch_bounds__(256) k_mlp1(
        const float* __restrict__ inb,
        const float* __restrict__ W1, const float* __restrict__ b1,
        float* __restrict__ hid) {
    __shared__ float sIn[64][HD + 4];
    __shared__ float sW1[HD * HD2];
    __shared__ float sb1[HD2];
    int tid = threadIdx.x;
    int n0 = blockIdx.x * 64;
    for (int i = tid; i < HD * HD2; i += 256) sW1[i] = W1[i];
    if (tid < HD2) sb1[tid] = b1[tid];
    for (int i = tid; i < 64 * (HD / 4); i += 256) {
        int n = i >> 4, fq = i & 15;
        int gn = n0 + n;
        float4 v = (gn < N_NODES)
            ? reinterpret_cast<const float4*>(inb + (size_t)gn * HD)[fq]
            : make_float4(0.f, 0.f, 0.f, 0.f);
        sIn[n][fq * 4 + 0] = v.x; sIn[n][fq * 4 + 1] = v.y;
        sIn[n][fq * 4 + 2] = v.z; sIn[n][fq * 4 + 3] = v.w;
    }
    __syncthreads();
    int ng = tid >> 5, jg = tid & 31;
    int nb = ng * 8, jb = jg * 4;
    float acc[8][4];
#pragma unroll
    for (int i = 0; i < 8; i++)
#pragma unroll
        for (int q = 0; q < 4; q++) acc[i][q] = sb1[jb + q];
#pragma unroll 4
    for (int f = 0; f < HD; f++) {
        float4 w = *reinterpret_cast<const float4*>(&sW1[f * HD2 + jb]);
        float xv[8];
#pragma unroll
        for (int i = 0; i < 8; i++) xv[i] = sIn[nb + i][f];
#pragma unroll
        for (int i = 0; i < 8; i++) {
            acc[i][0] += xv[i] * w.x;
            acc[i][1] += xv[i] * w.y;
            acc[i][2] += xv[i] * w.z;
            acc[i][3] += xv[i] * w.w;
        }
    }
#pragma unroll
    for (int i = 0; i < 8; i++) {
        int gn = n0 + nb + i;
        if (gn < N_NODES) {
            float4 o;
            o.x = fmaxf(acc[i][0], 0.f);
            o.y = fmaxf(acc[i][1], 0.f);
            o.z = fmaxf(acc[i][2], 0.f);
            o.w = fmaxf(acc[i][3], 0.f);
            *reinterpret_cast<float4*>(hid + (size_t)gn * HD2 + jb) = o;
        }
    }
}

// ---- MLP stage 2: h'[n][j] = relu(hid[n][:] @ W2[:, j] + b2[j]), K=128, J=64.
__global__ void __launch_bounds__(256) k_mlp2(
        const float* __restrict__ hid,
        const float* __restrict__ W2, const float* __restrict__ b2,
        float* __restrict__ hout) {
    __shared__ float sH[64][HD2 + 4];
    __shared__ float sW2[HD2 * HD];
    __shared__ float sb2[HD];
    int tid = threadIdx.x;
    int n0 = blockIdx.x * 64;
    for (int i = tid; i < HD2 * HD; i += 256) sW2[i] = W2[i];
    if (tid < HD) sb2[tid] = b2[tid];
    for (int i = tid; i < 64 * (HD2 / 4); i += 256) {
        int n = i >> 5, fq = i & 31;
        int gn = n0 + n;
        float4 v = (gn < N_NODES)
            ? reinterpret_cast<const float4*>(hid + (size_t)gn * HD2)[fq]
            : make_float4(0.f, 0.f, 0.f, 0.f);
        sH[n][fq * 4 + 0] = v.x; sH[n][fq * 4 + 1] = v.y;
        sH[n][fq * 4 + 2] = v.z; sH[n][fq * 4 + 3] = v.w;
    }
    __syncthreads();
    int ng = tid >> 4, jg = tid & 15;
    int nb = ng * 4, jb = jg * 4;
    float acc[4][4];
#pragma unroll
    for (int i = 0; i < 4; i++)
#pragma unroll
        for (int q = 0; q < 4; q++) acc[i][q] = sb2[jb + q];
#pragma unroll 4
    for (int f = 0; f < HD2; f++) {
        float4 w = *reinterpret_cast<const float4*>(&sW2[f * HD + jb]);
        float xv[4];
#pragma unroll
        for (int i = 0; i < 4; i++) xv[i] = sH[nb + i][f];
#pragma unroll
        for (int i = 0; i < 4; i++) {
            acc[i][0] += xv[i] * w.x;
            acc[i][1] += xv[i] * w.y;
            acc[i][2] += xv[i] * w.z;
            acc[i][3] += xv[i] * w.w;
        }
    }
#pragma unroll
    for (int i = 0; i < 4; i++) {
        int gn = n0 + nb + i;
        if (gn < N_NODES) {
            float4 o;
            o.x = fmaxf(acc[i][0], 0.f);
            o.y = fmaxf(acc[i][1], 0.f);
            o.z = fmaxf(acc[i][2], 0.f);
            o.w = fmaxf(acc[i][3], 0.f);
            *reinterpret_cast<float4*>(hout + (size_t)gn * HD + jb) = o;
        }
    }
}

// batch is sorted -> graph g owns contiguous node range [gstart[g], gstart[g+1]).
__global__ void __launch_bounds__(256) k_gstart(
        const int* __restrict__ batch, int* __restrict__ gstart) {
    int g = blockIdx.x * 256 + threadIdx.x;
    if (g > N_GRAPHS) return;
    int lo = 0, hi = N_NODES;
    while (lo < hi) {
        int mid = (lo + hi) >> 1;
        if (batch[mid] < g) lo = mid + 1; else hi = mid;
    }
    gstart[g] = lo;
}

// One wave per graph, lane = feature: pooled[g][f] = mean over node range.
__global__ void __launch_bounds__(256) k_pool(
        const float* __restrict__ h, const int* __restrict__ gstart,
        float* __restrict__ pooled) {
    int g = blockIdx.x * 4 + (threadIdx.x >> 6);
    if (g >= N_GRAPHS) return;
    int f = threadIdx.x & 63;
    int b = gstart[g], e = gstart[g + 1];
    float s = 0.f;
    for (int n = b; n < e; n++) s += h[(size_t)n * HD + f];
    float cnt = fmaxf((float)(e - b), 1.f);
    pooled[(size_t)g * HD + f] = s / cnt;
}

__global__ void __launch_bounds__(64) k_head(
        const float* __restrict__ pooled, const float* __restrict__ gattr,
        const float* __restrict__ d1W, const float* __restrict__ d1b,
        const float* __restrict__ d2W, const float* __restrict__ d2b,
        const float* __restrict__ oW, const float* __restrict__ ob,
        float* __restrict__ out) {
    int g = blockIdx.x;
    __shared__ float si[HD + F_GRAPH];
    __shared__ float s1[32], s2[32];
    int t = threadIdx.x;
    if (t < HD) si[t] = pooled[(size_t)g * HD + t];
    if (t < F_GRAPH) si[HD + t] = gattr[(size_t)g * F_GRAPH + t];
    __syncthreads();
    if (t < 32) {
        float acc = d1b[t];
        for (int i = 0; i < HD + F_GRAPH; i++) acc += si[i] * d1W[i * 32 + t];
        s1[t] = fmaxf(acc, 0.f);
    }
    __syncthreads();
    if (t < 32) {
        float acc = d2b[t];
        for (int i = 0; i < 32; i++) acc += s1[i] * d2W[i * 32 + t];
        s2[t] = fmaxf(acc, 0.f);
    }
    __syncthreads();
    if (t == 0) {
        float acc = ob[0];
        for (int i = 0; i < 32; i++) acc += s2[i] * oW[i];
        out[g] = 1.f / (1.f + __expf(-acc));
    }
}

extern "C" void kernel_launch(void* const* d_in, const int* in_sizes, int n_in,
                              void* d_out, int out_size, void* d_ws, size_t ws_size,
                              hipStream_t stream) {
    const float* x     = (const float*)d_in[0];
    const float* eattr = (const float*)d_in[1];
    const float* gattr = (const float*)d_in[2];
    const int*   eidx  = (const int*)d_in[3];
    const int*   batch = (const int*)d_in[4];
    const float* nodeW = (const float*)d_in[5];
    const float* nodeb = (const float*)d_in[6];
    const float* edgeW = (const float*)d_in[7];
    const float* edgeb = (const float*)d_in[8];
    const float* cW1[3] = {(const float*)d_in[9],  (const float*)d_in[13], (const float*)d_in[17]};
    const float* cb1[3] = {(const float*)d_in[10], (const float*)d_in[14], (const float*)d_in[18]};
    const float* cW2[3] = {(const float*)d_in[11], (const float*)d_in[15], (const float*)d_in[19]};
    const float* cb2[3] = {(const float*)d_in[12], (const float*)d_in[16], (const float*)d_in[20]};
    const float* d1W = (const float*)d_in[21];
    const float* d1b = (const float*)d_in[22];
    const float* d2W = (const float*)d_in[23];
    const float* d2b = (const float*)d_in[24];
    const float* oW  = (const float*)d_in[25];
    const float* ob  = (const float*)d_in[26];

    const int* src = eidx;
    const int* dst = eidx + N_EDGES;

    // workspace layout
    char* p = (char*)d_ws;
    float* h      = (float*)p; p += (size_t)N_NODES * HD * 4;       // 25.6 MB
    float* outb   = (float*)p; p += (size_t)N_NODES * HD * 4;       // 25.6 MB
    float* hid    = (float*)p; p += (size_t)N_NODES * HD2 * 4;      // 51.2 MB
    float* ea_lin = (float*)p; p += (size_t)N_EDGES * F_EDGE * 4;   // 51.2 MB
    float* pooled = (float*)p; p += (size_t)N_GRAPHS * HD * 4;
    int*   off    = (int*)p;   p += (size_t)(N_NODES + 1) * 4;
    int*   cursor = (int*)p;   p += (size_t)N_NODES * 4;
    int*   gstart = (int*)p;   p += (size_t)(N_GRAPHS + 1) * 4;
    int*   perm   = (int*)p;   p += (size_t)N_EDGES * 4;
    int*   psrc   = (int*)p;   p += (size_t)N_EDGES * 4;
    int*   bsum   = (int*)p;   p += (size_t)(SCAN_NBLK + 1) * 4;
    int*   bpre   = (int*)p;   p += (size_t)(SCAN_NBLK + 1) * 4;

    const int EB = (N_EDGES + 255) / 256;
    const int NB64 = (N_NODES + 63) / 64;

    k_node_embed<<<(N_NODES * HD + 255) / 256, 256, 0, stream>>>(x, nodeW, nodeb, h);

    // CSR build
    hipMemsetAsync(cursor, 0, (size_t)N_NODES * 4, stream);
    k_hist<<<EB, 256, 0, stream>>>(dst, cursor);
    k_scan1<<<SCAN_NBLK, 256, 0, stream>>>(cursor, bsum);
    k_scan2<<<1, 512, 0, stream>>>(bsum, bpre);
    k_scan3<<<SCAN_NBLK, 256, 0, stream>>>(cursor, bpre, off);
    hipMemcpyAsync(cursor, off, (size_t)N_NODES * 4, hipMemcpyDeviceToDevice, stream);
    k_scatter<<<EB, 256, 0, stream>>>(src, dst, cursor, perm, psrc);
    k_gather_ea<<<(int)(((long long)N_EDGES * F_EDGE + 255) / 256), 256, 0, stream>>>(
        perm, eattr, ea_lin);

    for (int l = 0; l < 3; l++) {
        k_gen_agg<<<(N_NODES + 3) / 4, 256, 0, stream>>>(
            h, off, psrc, ea_lin, edgeW, edgeb, outb);
        k_mlp1<<<NB64, 256, 0, stream>>>(outb, cW1[l], cb1[l], hid);
        k_mlp2<<<NB64, 256, 0, stream>>>(hid, cW2[l], cb2[l], h);
    }

    k_gstart<<<(N_GRAPHS + 256) / 256, 256, 0, stream>>>(batch, gstart);
    k_pool<<<(N_GRAPHS + 3) / 4, 256, 0, stream>>>(h, gstart, pooled);
    k_head<<<N_GRAPHS, 64, 0, stream>>>(pooled, gattr,
                                        d1W, d1b, d2W, d2b, oW, ob,
                                        (float*)d_out);
}